// Round 5
// baseline (204.730 us; speedup 1.0000x reference)
//
#include <hip/hip_runtime.h>

typedef _Float16 half8 __attribute__((ext_vector_type(8)));
typedef float floatx4 __attribute__((ext_vector_type(4)));

#define IMG   3136      // 56*56
#define PIMG  3364      // 58*58
#define XP_ELEMS (32 * 58 * 58 * 128)   // 13,778,944 fp16
#define WQ_ELEMS (9 * 256 * 128)        // 294,912 fp16

#define AS1 __attribute__((address_space(1)))
#define AS3 __attribute__((address_space(3)))

// ---------------- merged pre-pass (unchanged from R4, verified) ----------------
__global__ __launch_bounds__(256) void prep_kernel(const float* __restrict__ x,
                                                   const float* __restrict__ W,
                                                   _Float16* __restrict__ xp,
                                                   _Float16* __restrict__ wq) {
    const int bid = blockIdx.x;
    const int t   = threadIdx.x;
    if (bid >= 1856) {
        // ---- quant part: W -> staging-order swizzled fp16 ----
        int U = (bid - 1856) * 256 + t;
        int l  = U & 63;
        int wv = (U >> 6) & 7;
        int g  = (U >> 9) & 1;
        int h  = (U >> 10) & 1;
        int T  = U >> 11;                 // 0..17
        int rs = T >> 1, kt = T & 1;
        int k  = h * 128 + g * 64 + wv * 8 + (l >> 3);
        int c0 = kt * 64 + (((l & 7) ^ ((l >> 3) & 7)) * 8);
        _Float16* d = wq + (long)U * 8;
        #pragma unroll
        for (int j = 0; j < 8; ++j)
            d[j] = (_Float16)rintf(W[(k * 128 + c0 + j) * 9 + rs] * 128.0f);
        return;
    }
    // ---- pad part ----
    const int hh = bid % 58;
    const int n  = bid / 58;
    _Float16* rowbase = xp + ((long)(n * 58 + hh) * 58) * 128;

    if (hh == 0 || hh == 57) {
        #pragma unroll
        for (int i = 0; i < 4; ++i) {
            int idx = i * 256 + t;
            if (idx < 928) *(half8*)(rowbase + idx * 8) = (half8)(_Float16)0.0f;
        }
        return;
    }

    __shared__ _Float16 tile[128 * 57];
    const int h = hh - 1;

    #pragma unroll
    for (int p = 0; p < 7; ++p) {
        int idx = p * 256 + t;              // 7*256 = 1792
        int c   = idx / 14;
        int w4  = (idx % 14) * 4;
        const float4 v = *(const float4*)(x + ((long)(n * 128 + c) * 56 + h) * 56 + w4);
        _Float16* d = tile + c * 57 + w4;
        d[0] = (_Float16)v.x; d[1] = (_Float16)v.y;
        d[2] = (_Float16)v.z; d[3] = (_Float16)v.w;
    }
    __syncthreads();

    #pragma unroll
    for (int p = 0; p < 4; ++p) {
        int idx = p * 256 + t;
        if (idx < 896) {
            int ww = idx >> 4;
            int c0 = (idx & 15) * 8;
            half8 v;
            #pragma unroll
            for (int j = 0; j < 8; ++j) v[j] = tile[(c0 + j) * 57 + ww];
            *(half8*)(rowbase + (ww + 1) * 128 + c0) = v;
        }
    }
    if (t < 32) {
        int ww = (t >> 4) ? 57 : 0;
        int c0 = (t & 15) * 8;
        *(half8*)(rowbase + ww * 128 + c0) = (half8)(_Float16)0.0f;
    }
}

// ---------------- main: implicit GEMM, M=256, N=100352, K=1152 ----------------
// True m201 phase discipline this round (R4 was the coarse split, which m196
// measured as the losing variant): per K-tile, 4 phases each
//   {ds_read subtile -> stage-issue -> lgkmcnt(0) -> setprio(1) -> 16 MFMA ->
//    setprio(0) -> s_barrier}
// plus vmcnt(0)+barrier at tile top. Per-phase barriers phase-lock the waves
// so one wave's LDS reads overlap the other's MFMA cluster (T3->T5 mechanism,
// m218b). All 8 stage loads of T+1 issue in phases 0-1 of T (>=700cyc cover),
// so the tile-top vmcnt(0) waits only fully-aged loads. Layouts/staging/
// swizzle/epilogue byte-identical to R4 (passed, 0 bank conflicts).
__global__ __launch_bounds__(512, 2) void conv_mfma_kernel(
    const _Float16* __restrict__ xp, const _Float16* __restrict__ wq,
    const float* __restrict__ b, float* __restrict__ out)
{
    __shared__ __align__(16) _Float16 smem[65536];  // 2 bufs x (A 16384 + B 16384) = 128 KB

    const int tid = threadIdx.x;
    const int l   = tid & 63;
    const int wv  = tid >> 6;        // 0..7
    const int wm  = wv & 1;          // M-half (128 filters)
    const int wn  = wv >> 1;         // N-quarter (64 pixels)
    int bx  = blockIdx.x;
    bx = (bx & 7) * 49 + (bx >> 3);  // XCD swizzle (392 = 8*49, bijective)

    const int lr3  = l >> 3;
    const int l7   = l & 7;
    const int l47  = l >> 4;
    const int lswz = ((l & 7) ^ (lr3 & 7)) * 16;   // staged-chunk byte offset (XOR pre-swizzle)

    // B staging source bases: (h,g) -> pixel row = bx*256 + h*128 + g*64 + wv*8 + (l>>3)
    long pbB[4];
    #pragma unroll
    for (int hg = 0; hg < 4; ++hg) {
        const int pix = bx * 256 + hg * 64 + wv * 8 + lr3;
        const int n = pix / IMG, hw = pix % IMG;
        pbB[hg] = (long)(n * PIMG + (hw / 56) * 58 + (hw % 56)) * 256 + lswz;
    }
    // A staging source: wq flat pos = (((T*2+h)*2+g)*8 + wv)*1024 + l*16 bytes
    const long abase = (long)wv * 1024 + l * 16;

    floatx4 acc[8][4] = {};

    // stage one A half-tile (2 global_load_lds calls, g=0/1)
    auto stageA = [&](int T, int h, int pbuf) {
        const char* src = (const char*)wq + (long)((T * 2 + h) * 2) * 8192 + abase;
        _Float16* dst = smem + pbuf * 32768 + (h * 128 + wv * 8) * 64;
        __builtin_amdgcn_global_load_lds((AS1 void*)src,          (AS3 void*)dst,          16, 0, 0);
        __builtin_amdgcn_global_load_lds((AS1 void*)(src + 8192), (AS3 void*)(dst + 4096), 16, 0, 0);
    };
    // stage one B half-tile (2 calls, g=0/1)
    auto stageB = [&](int T, int h, int pbuf) {
        const int rs = T >> 1, kt = T & 1;
        const int r  = (rs * 11) >> 5;          // rs/3 for rs in [0,9)
        const int s2 = rs - r * 3;
        const long toff = (long)(r * 58 + s2) * 256 + kt * 128;
        const char* xb = (const char*)xp + toff;
        _Float16* dst = smem + pbuf * 32768 + 16384 + (h * 128 + wv * 8) * 64;
        __builtin_amdgcn_global_load_lds((AS1 void*)(xb + pbB[h * 2 + 0]), (AS3 void*)dst,          16, 0, 0);
        __builtin_amdgcn_global_load_lds((AS1 void*)(xb + pbB[h * 2 + 1]), (AS3 void*)(dst + 4096), 16, 0, 0);
    };

    const int arow = wm * 128 + (l & 15);
    const int brow = wn * 64 + (l & 15);

    // One phase: ds_read af subtile (4 x b128), stage-issue, lgkmcnt(0),
    // setprio-wrapped 16 MFMA, trailing barrier. q literal -> static acc idx.
    #define PHASE(q, STAGE_STMT) { \
        half8 af0[2], af1[2]; \
        _Pragma("unroll") for (int i = 0; i < 2; ++i) { \
            const int mi = (q) * 2 + i; \
            af0[i] = *(const half8*)(As + (arow + mi * 16) * 64 + ((0 + l47) ^ l7) * 8); \
            af1[i] = *(const half8*)(As + (arow + mi * 16) * 64 + ((4 + l47) ^ l7) * 8); \
        } \
        STAGE_STMT \
        asm volatile("s_waitcnt lgkmcnt(0)" ::: "memory"); \
        __builtin_amdgcn_s_setprio(1); \
        _Pragma("unroll") for (int i = 0; i < 2; ++i) { \
            const int mi = (q) * 2 + i; \
            _Pragma("unroll") for (int ni = 0; ni < 4; ++ni) { \
                acc[mi][ni] = __builtin_amdgcn_mfma_f32_16x16x32_f16(af0[i], bf[ni][0], acc[mi][ni], 0, 0, 0); \
                acc[mi][ni] = __builtin_amdgcn_mfma_f32_16x16x32_f16(af1[i], bf[ni][1], acc[mi][ni], 0, 0, 0); \
            } \
        } \
        __builtin_amdgcn_s_setprio(0); \
        asm volatile("s_barrier" ::: "memory"); \
    }

    // prologue: stage K-tile 0 into buf 0 (8 calls)
    stageA(0, 0, 0); stageA(0, 1, 0); stageB(0, 0, 0); stageB(0, 1, 0);

    #pragma unroll 2
    for (int T = 0; T < 18; ++T) {
        const int pb = T & 1;
        const _Float16* As = smem + pb * 32768;
        const _Float16* Bs = As + 16384;
        // tile top: T's 8 loads are the only VMEM in flight and fully aged
        asm volatile("s_waitcnt vmcnt(0)" ::: "memory");
        asm volatile("s_barrier" ::: "memory");       // tile T data visible to all
        // bf for the whole tile (8 x b128), covered by phase 0's lgkmcnt(0)
        half8 bf[4][2];
        #pragma unroll
        for (int ni = 0; ni < 4; ++ni) {
            bf[ni][0] = *(const half8*)(Bs + (brow + ni * 16) * 64 + ((0 + l47) ^ l7) * 8);
            bf[ni][1] = *(const half8*)(Bs + (brow + ni * 16) * 64 + ((4 + l47) ^ l7) * 8);
        }
        PHASE(0, { if (T < 17) { stageA(T + 1, 0, pb ^ 1); stageA(T + 1, 1, pb ^ 1); } })
        PHASE(1, { if (T < 17) { stageB(T + 1, 0, pb ^ 1); stageB(T + 1, 1, pb ^ 1); } })
        PHASE(2, { })
        PHASE(3, { })
    }
    #undef PHASE

    // epilogue: D[row=(l>>4)*4+reg = filter][col=l&15 = pixel]
    #pragma unroll
    for (int mi = 0; mi < 8; ++mi) {
        const int kb = wm * 128 + mi * 16 + (l >> 4) * 4;
        #pragma unroll
        for (int rg = 0; rg < 4; ++rg) {
            const int k = kb + rg;
            const float bq = rintf(b[k] * 128.0f);
            #pragma unroll
            for (int ni = 0; ni < 4; ++ni) {
                const int pix = bx * 256 + wn * 64 + ni * 16 + (l & 15);
                const int n  = pix / IMG;
                const int pr = pix - n * IMG;
                out[((long)n * 256 + k) * IMG + pr] = acc[mi][ni][rg] * (1.0f / 128.0f) + bq;
            }
        }
    }
}

// ---------------- fallback (ws too small): direct conv, correct but slow ----------------
__global__ void conv_fallback_kernel(const float* __restrict__ x, const float* __restrict__ W,
                                     const float* __restrict__ b, float* __restrict__ out)
{
    __shared__ float wsm[1152];
    const int k = blockIdx.y;
    for (int i = threadIdx.x; i < 1152; i += 256)
        wsm[i] = rintf(W[k * 1152 + i] * 128.0f);
    __syncthreads();
    const int pix = blockIdx.x * 256 + threadIdx.x;
    const int n = pix / IMG, hw = pix % IMG;
    const int h = hw / 56, w = hw % 56;
    float acc = 0.0f;
    for (int c = 0; c < 128; ++c) {
        const float* xr = x + ((n * 128 + c) * 56) * 56;
        const float* wr = wsm + c * 9;
        #pragma unroll
        for (int r = 0; r < 3; ++r) {
            const int hh = h + r - 1;
            if ((unsigned)hh >= 56u) continue;
            #pragma unroll
            for (int s = 0; s < 3; ++s) {
                const int ww = w + s - 1;
                if ((unsigned)ww >= 56u) continue;
                acc += xr[hh * 56 + ww] * wr[r * 3 + s];
            }
        }
    }
    out[((long)n * 256 + k) * IMG + hw] = acc * (1.0f / 128.0f) + rintf(b[k] * 128.0f);
}

extern "C" void kernel_launch(void* const* d_in, const int* in_sizes, int n_in,
                              void* d_out, int out_size, void* d_ws, size_t ws_size,
                              hipStream_t stream) {
    const float* x = (const float*)d_in[0];
    const float* W = (const float*)d_in[1];
    const float* b = (const float*)d_in[2];
    float* out = (float*)d_out;

    const size_t need = (size_t)XP_ELEMS * 2 + (size_t)WQ_ELEMS * 2;   // 28,147,712 B
    if (ws_size >= need) {
        _Float16* xp = (_Float16*)d_ws;
        _Float16* wq = xp + XP_ELEMS;
        prep_kernel<<<2000, 256, 0, stream>>>(x, W, xp, wq);
        conv_mfma_kernel<<<dim3(392), 512, 0, stream>>>(xp, wq, b, out);
    } else {
        conv_fallback_kernel<<<dim3(392, 256), 256, 0, stream>>>(x, W, b, out);
    }
}